// Round 8
// baseline (1287.363 us; speedup 1.0000x reference)
//
#include <hip/hip_runtime.h>

#define D     12
#define ASTR  13     // LDS acc stride (coprime with 32 banks)
#define NPB   128    // nodes per bucket (rloc = 7 bits)
#define CAP   9216   // max bucket size held in LDS
#define EPB   16384  // edges per block for passes A/B
#define ABLK  256
#define SBLK  256
#define CBLK  256

// swizzle for sorted2 indices: breaks the per-thread stride-32 bank pattern.
// Involution (applied at both write and read); flips only low 5 bits.
#define SWZ(p) ((p) ^ (((p) >> 5) & 31))

// ---------------- pass A: per-block bucket histogram ----------------
__global__ __launch_bounds__(ABLK) void passA_hist(
    const int* __restrict__ receivers, long E, int nbuck,
    int* __restrict__ cnt /* [nblk][nbuck], row-major */)
{
    extern __shared__ int hist[]; // nbuck ints
    for (int i = threadIdx.x; i < nbuck; i += ABLK) hist[i] = 0;
    __syncthreads();
    long e0 = (long)blockIdx.x * EPB;
    long e1 = e0 + EPB; if (e1 > E) e1 = E;
    for (long e = e0 + threadIdx.x; e < e1; e += ABLK) {
        int r = receivers[e];
        atomicAdd(&hist[r >> 7], 1);
    }
    __syncthreads();
    int* row = cnt + (long)blockIdx.x * nbuck;
    for (int i = threadIdx.x; i < nbuck; i += ABLK) row[i] = hist[i];
}

// ---------------- pass S1: exclusive scan down each bucket column ----------------
__global__ __launch_bounds__(SBLK) void passS1_colscan(
    int* __restrict__ cnt, int nblk, int nbuck, int* __restrict__ totals)
{
    int b = blockIdx.x;
    int t = threadIdx.x;
    __shared__ int csum[SBLK];
    int per = (nblk + SBLK - 1) / SBLK;
    int i0 = t * per;
    int i1 = i0 + per; if (i1 > nblk) i1 = nblk;
    int s = 0;
    for (int i = i0; i < i1; ++i) s += cnt[(long)i * nbuck + b];
    csum[t] = s;
    __syncthreads();
    for (int off = 1; off < SBLK; off <<= 1) {
        int add = (t >= off) ? csum[t - off] : 0;
        __syncthreads();
        csum[t] += add;
        __syncthreads();
    }
    int run = csum[t] - s;
    for (int i = i0; i < i1; ++i) {
        long a = (long)i * nbuck + b;
        int tmp = cnt[a];
        cnt[a] = run;
        run += tmp;
    }
    if (t == SBLK - 1) totals[b] = csum[SBLK - 1];
}

// ---------------- pass S2: exclusive scan over bucket totals ----------------
__global__ __launch_bounds__(1024) void passS2_basescan(
    const int* __restrict__ totals, int* __restrict__ base, int nbuck)
{
    __shared__ int sh[1024];
    int t = threadIdx.x;
    int v = (t < nbuck) ? totals[t] : 0;
    sh[t] = v;
    __syncthreads();
    for (int off = 1; off < 1024; off <<= 1) {
        int add = (t >= off) ? sh[t - off] : 0;
        __syncthreads();
        sh[t] += add;
        __syncthreads();
    }
    if (t < nbuck) base[t] = sh[t] - v;
}

// ---------------- pass B: scatter edge ids into bucket-sorted order ----------------
__global__ __launch_bounds__(ABLK) void passB_scatter(
    const int* __restrict__ receivers, long E, int nbuck,
    const int* __restrict__ cnt, const int* __restrict__ base,
    unsigned int* __restrict__ sorted)
{
    extern __shared__ int cur[];
    const int* row = cnt + (long)blockIdx.x * nbuck;
    for (int i = threadIdx.x; i < nbuck; i += ABLK) cur[i] = row[i] + base[i];
    __syncthreads();
    long e0 = (long)blockIdx.x * EPB;
    long e1 = e0 + EPB; if (e1 > E) e1 = E;
    for (long e = e0 + threadIdx.x; e < e1; e += ABLK) {
        int r = receivers[e];
        int b = r >> 7;
        int pos = atomicAdd(&cur[b], 1);
        sorted[pos] = ((unsigned)e << 7) | (unsigned)(r & 127);
    }
}

// -------- helpers --------
__device__ __forceinline__ void build_weights(
    int t,
    const float* __restrict__ bn_scale, const float* __restrict__ bn_bias,
    const float* __restrict__ bn_mean,  const float* __restrict__ bn_var,
    const float* __restrict__ W1, const float* __restrict__ b1,
    const float* __restrict__ W2, const float* __restrict__ b2,
    float* sW1, float* sW2, float* sB1, float* sB2)
{
    if (t < D * D) {
        int d = t / D;
        float a = bn_scale[d] * rsqrtf(bn_var[d] + 1e-5f);
        sW1[t] = a * W1[t];
        sW2[t] = W2[t];
    }
    if (t < D) {
        float acc = b1[t];
        #pragma unroll
        for (int d = 0; d < D; ++d) {
            float a = bn_scale[d] * rsqrtf(bn_var[d] + 1e-5f);
            float c = bn_bias[d] - bn_mean[d] * a;
            acc += c * W1[d * D + t];
        }
        sB1[t] = acc;
        sB2[t] = b2[t];
    }
}

__device__ __forceinline__ void mlp12(
    const float x[D],
    const float* sW1, const float* sW2, const float* sB1, const float* sB2,
    float y[D])
{
    float h[D];
    #pragma unroll
    for (int j = 0; j < D; ++j) h[j] = sB1[j];
    #pragma unroll
    for (int d = 0; d < D; ++d) {
        float xd = x[d];
        #pragma unroll
        for (int j = 0; j < D; ++j) h[j] = fmaf(xd, sW1[d * D + j], h[j]);
    }
    #pragma unroll
    for (int j = 0; j < D; ++j) h[j] = fmaxf(h[j], 0.f);
    #pragma unroll
    for (int j = 0; j < D; ++j) y[j] = sB2[j];
    #pragma unroll
    for (int d = 0; d < D; ++d) {
        float hd = h[d];
        #pragma unroll
        for (int j = 0; j < D; ++j) y[j] = fmaf(hd, sW2[d * D + j], y[j]);
    }
}

// ---------------- pass C: in-LDS node sort + register accumulation ----------------
// Round-8 changes vs round-7:
//  * __launch_bounds__(256,3): cap VGPR at ~170 -> 3 waves/SIMD (was 204 VGPR,
//    2 waves/SIMD). 3 waves x ~640 VALU-cy per edge > 900-cy HBM latency, so
//    TLP alone hides the gather; the explicit row prefetch (the VGPR hog) is
//    removed.
//  * sorted2 index swizzle: per-thread ranges stride ~32 made every LDS read
//    32-way bank-conflicted (4.58M conflict cycles in r7).
__global__ __launch_bounds__(CBLK, 3) void passC_nodesort(
    const float* __restrict__ edges,
    const unsigned int* __restrict__ sortedG,
    const int* __restrict__ base, const int* __restrict__ totals,
    const float* __restrict__ bn_scale, const float* __restrict__ bn_bias,
    const float* __restrict__ bn_mean,  const float* __restrict__ bn_var,
    const float* __restrict__ W1, const float* __restrict__ b1,
    const float* __restrict__ W2, const float* __restrict__ b2,
    float* __restrict__ out, long total /* N*D */)
{
    __shared__ float sW1[D * D], sW2[D * D], sB1[D], sB2[D];
    __shared__ int hist[NPB];
    __shared__ int off[NPB + 1];
    __shared__ int cur[NPB];
    __shared__ unsigned sorted2[CAP];
    __shared__ float facc[NPB * ASTR];

    const int t = threadIdx.x;
    build_weights(t, bn_scale, bn_bias, bn_mean, bn_var, W1, b1, W2, b2,
                  sW1, sW2, sB1, sB2);
    for (int i = t; i < NPB * ASTR; i += CBLK) facc[i] = 0.f;
    if (t < NPB) hist[t] = 0;
    __syncthreads();

    const int b = blockIdx.x;
    const int s0 = base[b];
    const int n  = totals[b];

    if (n <= CAP) {
        // phase 1: node histogram
        for (int k = t; k < n; k += CBLK)
            atomicAdd(&hist[sortedG[s0 + k] & (NPB - 1)], 1);
        __syncthreads();

        // phase 2: exclusive scan over 128 counters
        int myh = (t < NPB) ? hist[t] : 0;
        if (t < NPB) off[t] = myh;
        __syncthreads();
        for (int d2 = 1; d2 < NPB; d2 <<= 1) {
            int add = 0;
            if (t < NPB && t >= d2) add = off[t - d2];
            __syncthreads();
            if (t < NPB) off[t] += add;
            __syncthreads();
        }
        if (t < NPB) cur[t] = off[t] - myh;
        __syncthreads();
        if (t < NPB) off[t] = cur[t];
        if (t == 0) off[NPB] = n;
        __syncthreads();

        // phase 3: scatter edge indices into node-sorted (swizzled) LDS order
        for (int k = t; k < n; k += CBLK) {
            unsigned e = sortedG[s0 + k];
            int pos = atomicAdd(&cur[e & (NPB - 1)], 1);
            sorted2[SWZ(pos)] = e >> 7;
        }
        __syncthreads();

        // phase 4: contiguous-range gather + MLP + register accumulation
        const int per = (n + CBLK - 1) / CBLK;
        int k0 = t * per;
        int k1 = k0 + per; if (k1 > n) k1 = n;
        if (k0 < k1) {
            int cu = 0;
            while (off[cu + 1] <= k0) ++cu;
            int nodeEnd = off[cu + 1];

            float ac[D];
            #pragma unroll
            for (int j = 0; j < D; ++j) ac[j] = 0.f;

            for (int k = k0; k < k1; ++k) {
                if (k >= nodeEnd) {
                    #pragma unroll
                    for (int j = 0; j < D; ++j) {
                        atomicAdd(&facc[cu * ASTR + j], ac[j]);
                        ac[j] = 0.f;
                    }
                    do { ++cu; } while (off[cu + 1] <= k);
                    nodeEnd = off[cu + 1];
                }
                unsigned idx = sorted2[SWZ(k)];
                const float4* p = reinterpret_cast<const float4*>(edges + (long)idx * D);
                float4 c0 = p[0], c1 = p[1], c2 = p[2];
                float x[D] = {c0.x, c0.y, c0.z, c0.w, c1.x, c1.y, c1.z, c1.w,
                              c2.x, c2.y, c2.z, c2.w};
                float y[D];
                mlp12(x, sW1, sW2, sB1, sB2, y);
                #pragma unroll
                for (int j = 0; j < D; ++j) ac[j] += y[j];
            }
            #pragma unroll
            for (int j = 0; j < D; ++j) atomicAdd(&facc[cu * ASTR + j], ac[j]);
        }
    } else {
        // oversized bucket: atomic path
        for (int k = t; k < n; k += CBLK) {
            unsigned e = sortedG[s0 + k];
            const float4* p = reinterpret_cast<const float4*>(edges + (long)(e >> 7) * D);
            float4 c0 = p[0], c1 = p[1], c2 = p[2];
            float x[D] = {c0.x, c0.y, c0.z, c0.w, c1.x, c1.y, c1.z, c1.w,
                          c2.x, c2.y, c2.z, c2.w};
            float y[D];
            mlp12(x, sW1, sW2, sB1, sB2, y);
            int rloc = (int)(e & (NPB - 1));
            #pragma unroll
            for (int j = 0; j < D; ++j) atomicAdd(&facc[rloc * ASTR + j], y[j]);
        }
    }
    __syncthreads();

    long obase = (long)b * (NPB * D);
    long cnt_w = total - obase; if (cnt_w > NPB * D) cnt_w = NPB * D;
    for (long i = t; i < cnt_w; i += CBLK)
        out[obase + i] = facc[((int)i / D) * ASTR + ((int)i % D)];
}

// ---------------- fallback: direct atomic scatter ----------------
#define EPT 4
__global__ __launch_bounds__(ABLK) void edge_mlp_scatter(
    const float* __restrict__ edges,
    const float* __restrict__ bn_scale, const float* __restrict__ bn_bias,
    const float* __restrict__ bn_mean,  const float* __restrict__ bn_var,
    const float* __restrict__ W1, const float* __restrict__ b1,
    const float* __restrict__ W2, const float* __restrict__ b2,
    const int* __restrict__ receivers, float* __restrict__ out, long E)
{
    __shared__ float sW1[D * D], sW2[D * D], sB1[D], sB2[D];
    const int t = threadIdx.x;
    build_weights(t, bn_scale, bn_bias, bn_mean, bn_var, W1, b1, W2, b2,
                  sW1, sW2, sB1, sB2);
    __syncthreads();
    const long basee = (long)blockIdx.x * (ABLK * EPT) + t;
    #pragma unroll
    for (int kk = 0; kk < EPT; ++kk) {
        long e = basee + (long)kk * ABLK;
        if (e >= E) continue;
        int r = receivers[e];
        const float4* p = reinterpret_cast<const float4*>(edges + e * D);
        float4 v0 = p[0], v1 = p[1], v2 = p[2];
        float x[D] = {v0.x, v0.y, v0.z, v0.w, v1.x, v1.y, v1.z, v1.w,
                      v2.x, v2.y, v2.z, v2.w};
        float y[D];
        mlp12(x, sW1, sW2, sB1, sB2, y);
        #pragma unroll
        for (int j = 0; j < D; ++j) atomicAdd(&out[(long)r * D + j], y[j]);
    }
}

extern "C" void kernel_launch(void* const* d_in, const int* in_sizes, int n_in,
                              void* d_out, int out_size, void* d_ws, size_t ws_size,
                              hipStream_t stream) {
    const float* edges     = (const float*)d_in[0];
    const float* bn_scale  = (const float*)d_in[1];
    const float* bn_bias   = (const float*)d_in[2];
    const float* bn_mean   = (const float*)d_in[3];
    const float* bn_var    = (const float*)d_in[4];
    const float* W1        = (const float*)d_in[5];
    const float* b1        = (const float*)d_in[6];
    const float* W2        = (const float*)d_in[7];
    const float* b2        = (const float*)d_in[8];
    const int*   receivers = (const int*)d_in[9];
    float*       out       = (float*)d_out;

    const long E = (long)in_sizes[0] / D;
    const int  N = out_size / D;

    const int  nbuck = (N + NPB - 1) >> 7;
    const long nblk  = (E + EPB - 1) / EPB;
    const size_t cntBytes = (size_t)nblk * (size_t)nbuck * 4u;
    const size_t need = cntBytes + 2u * (size_t)nbuck * 4u + (size_t)E * 4u + 512u;
    const long total = (long)N * D;

    const bool shapeOK = (nbuck <= 1024) && (E < (1L << 25));

    if (shapeOK && ws_size >= need) {
        char* w = (char*)d_ws;
        int* cnt    = (int*)w;  w += cntBytes;
        int* totals = (int*)w;  w += (size_t)nbuck * 4u;
        int* basep  = (int*)w;  w += (size_t)nbuck * 4u;
        unsigned int* sortedG = (unsigned int*)w;

        const size_t lds = (size_t)nbuck * 4u;
        passA_hist    <<<dim3((unsigned)nblk), dim3(ABLK), lds, stream>>>(receivers, E, nbuck, cnt);
        passS1_colscan<<<dim3((unsigned)nbuck), dim3(SBLK), 0, stream>>>(cnt, (int)nblk, nbuck, totals);
        passS2_basescan<<<dim3(1), dim3(1024), 0, stream>>>(totals, basep, nbuck);
        passB_scatter <<<dim3((unsigned)nblk), dim3(ABLK), lds, stream>>>(receivers, E, nbuck, cnt, basep, sortedG);
        passC_nodesort<<<dim3((unsigned)nbuck), dim3(CBLK), 0, stream>>>(
            edges, sortedG, basep, totals,
            bn_scale, bn_bias, bn_mean, bn_var, W1, b1, W2, b2, out, total);
        return;
    }

    (void)hipMemsetAsync(d_out, 0, (size_t)out_size * sizeof(float), stream);
    const long blocks = (E + (long)(ABLK * EPT) - 1) / (long)(ABLK * EPT);
    edge_mlp_scatter<<<dim3((unsigned)blocks), dim3(ABLK), 0, stream>>>(
        edges, bn_scale, bn_bias, bn_mean, bn_var, W1, b1, W2, b2,
        receivers, out, E);
}

// Round 9
// 486.240 us; speedup vs baseline: 2.6476x; 2.6476x over previous
//
#include <hip/hip_runtime.h>

#define D      12
#define ASTR   13     // LDS acc stride (coprime with 32 banks)
#define LOGNPB 6
#define NPB    64     // nodes per bucket
#define CAP    4608   // max bucket size in LDS (mean 4096 + 8 sigma)
#define EPB    16384  // edges per block for passes A/B
#define ABLK   256
#define SBLK   256
#define CBLK   256

// involution swizzle for sorted2 (flips low 5 bits by a row-derived mask)
#define SWZ(p) ((p) ^ (((p) >> 5) & 31))

// ---------------- pass A: per-block bucket histogram ----------------
__global__ __launch_bounds__(ABLK) void passA_hist(
    const int* __restrict__ receivers, long E, int nbuck,
    int* __restrict__ cnt /* [nblk][nbuck], row-major */)
{
    extern __shared__ int hist[]; // nbuck ints
    for (int i = threadIdx.x; i < nbuck; i += ABLK) hist[i] = 0;
    __syncthreads();
    long e0 = (long)blockIdx.x * EPB;
    long e1 = e0 + EPB; if (e1 > E) e1 = E;
    for (long e = e0 + threadIdx.x; e < e1; e += ABLK) {
        int r = receivers[e];
        atomicAdd(&hist[r >> LOGNPB], 1);
    }
    __syncthreads();
    int* row = cnt + (long)blockIdx.x * nbuck;
    for (int i = threadIdx.x; i < nbuck; i += ABLK) row[i] = hist[i];
}

// ---------------- pass S1: exclusive scan down each bucket column ----------------
__global__ __launch_bounds__(SBLK) void passS1_colscan(
    int* __restrict__ cnt, int nblk, int nbuck, int* __restrict__ totals)
{
    int b = blockIdx.x;
    int t = threadIdx.x;
    __shared__ int csum[SBLK];
    int per = (nblk + SBLK - 1) / SBLK;
    int i0 = t * per;
    int i1 = i0 + per; if (i1 > nblk) i1 = nblk;
    int s = 0;
    for (int i = i0; i < i1; ++i) s += cnt[(long)i * nbuck + b];
    csum[t] = s;
    __syncthreads();
    for (int off = 1; off < SBLK; off <<= 1) {
        int add = (t >= off) ? csum[t - off] : 0;
        __syncthreads();
        csum[t] += add;
        __syncthreads();
    }
    int run = csum[t] - s;
    for (int i = i0; i < i1; ++i) {
        long a = (long)i * nbuck + b;
        int tmp = cnt[a];
        cnt[a] = run;
        run += tmp;
    }
    if (t == SBLK - 1) totals[b] = csum[SBLK - 1];
}

// ---------------- pass S2: exclusive scan over bucket totals ----------------
__global__ __launch_bounds__(1024) void passS2_basescan(
    const int* __restrict__ totals, int* __restrict__ base, int nbuck)
{
    __shared__ int sh[2048];
    int t = threadIdx.x;
    int n2 = (nbuck + 1023) / 1024; // 1 or 2 elems per thread
    int v0 = (t < nbuck) ? totals[t] : 0;
    int v1 = (n2 > 1 && t + 1024 < nbuck) ? totals[t + 1024] : 0;
    sh[t] = v0; sh[t + 1024] = v1;
    __syncthreads();
    // serial-friendly scan done by thread 0 is too slow; Hillis-Steele over 2048
    for (int off = 1; off < 2048; off <<= 1) {
        int a0 = (t >= off) ? sh[t - off] : 0;
        int a1 = (t + 1024 >= off) ? sh[t + 1024 - off] : 0;
        __syncthreads();
        sh[t] += a0; sh[t + 1024] += a1;
        __syncthreads();
    }
    if (t < nbuck) base[t] = sh[t] - v0;
    if (n2 > 1 && t + 1024 < nbuck) base[t + 1024] = sh[t + 1024] - v1;
}

// ---------------- pass B: scatter edge ids into bucket-sorted order ----------------
__global__ __launch_bounds__(ABLK) void passB_scatter(
    const int* __restrict__ receivers, long E, int nbuck,
    const int* __restrict__ cnt, const int* __restrict__ base,
    unsigned int* __restrict__ sorted)
{
    extern __shared__ int cur[];
    const int* row = cnt + (long)blockIdx.x * nbuck;
    for (int i = threadIdx.x; i < nbuck; i += ABLK) cur[i] = row[i] + base[i];
    __syncthreads();
    long e0 = (long)blockIdx.x * EPB;
    long e1 = e0 + EPB; if (e1 > E) e1 = E;
    for (long e = e0 + threadIdx.x; e < e1; e += ABLK) {
        int r = receivers[e];
        int b = r >> LOGNPB;
        int pos = atomicAdd(&cur[b], 1);
        sorted[pos] = ((unsigned)e << LOGNPB) | (unsigned)(r & (NPB - 1));
    }
}

// -------- helpers --------
__device__ __forceinline__ void build_weights(
    int t,
    const float* __restrict__ bn_scale, const float* __restrict__ bn_bias,
    const float* __restrict__ bn_mean,  const float* __restrict__ bn_var,
    const float* __restrict__ W1, const float* __restrict__ b1,
    const float* __restrict__ W2, const float* __restrict__ b2,
    float* sW1, float* sW2, float* sB1, float* sB2)
{
    if (t < D * D) {
        int d = t / D;
        float a = bn_scale[d] * rsqrtf(bn_var[d] + 1e-5f);
        sW1[t] = a * W1[t];
        sW2[t] = W2[t];
    }
    if (t < D) {
        float acc = b1[t];
        #pragma unroll
        for (int d = 0; d < D; ++d) {
            float a = bn_scale[d] * rsqrtf(bn_var[d] + 1e-5f);
            float c = bn_bias[d] - bn_mean[d] * a;
            acc += c * W1[d * D + t];
        }
        sB1[t] = acc;
        sB2[t] = b2[t];
    }
}

__device__ __forceinline__ void mlp12(
    const float x[D],
    const float* sW1, const float* sW2, const float* sB1, const float* sB2,
    float y[D])
{
    float h[D];
    #pragma unroll
    for (int j = 0; j < D; ++j) h[j] = sB1[j];
    #pragma unroll
    for (int d = 0; d < D; ++d) {
        float xd = x[d];
        #pragma unroll
        for (int j = 0; j < D; ++j) h[j] = fmaf(xd, sW1[d * D + j], h[j]);
    }
    #pragma unroll
    for (int j = 0; j < D; ++j) h[j] = fmaxf(h[j], 0.f);
    #pragma unroll
    for (int j = 0; j < D; ++j) y[j] = sB2[j];
    #pragma unroll
    for (int d = 0; d < D; ++d) {
        float hd = h[d];
        #pragma unroll
        for (int j = 0; j < D; ++j) y[j] = fmaf(hd, sW2[d * D + j], y[j]);
    }
}

// ---------------- pass C: in-LDS node sort + register accumulation ----------------
// Round-9 vs round-7: NO launch_bounds cap (r4/r8 both spilled); instead the
// per-edge loop drops y[12] (second GEMM accumulates straight into ac) and the
// b2 bias is applied once per node at the final write as hist[node]*b2.
// NPB=64 doubles the grid (1563 blocks) for tail balance; LDS/block ~24KB.
__global__ __launch_bounds__(CBLK) void passC_nodesort(
    const float* __restrict__ edges,
    const unsigned int* __restrict__ sortedG,
    const int* __restrict__ base, const int* __restrict__ totals,
    const float* __restrict__ bn_scale, const float* __restrict__ bn_bias,
    const float* __restrict__ bn_mean,  const float* __restrict__ bn_var,
    const float* __restrict__ W1, const float* __restrict__ b1,
    const float* __restrict__ W2, const float* __restrict__ b2,
    float* __restrict__ out, long total /* N*D */)
{
    __shared__ float sW1[D * D], sW2[D * D], sB1[D], sB2[D];
    __shared__ int hist[NPB];
    __shared__ int off[NPB + 1];
    __shared__ int cur[NPB];
    __shared__ unsigned sorted2[CAP];
    __shared__ float facc[NPB * ASTR];

    const int t = threadIdx.x;
    build_weights(t, bn_scale, bn_bias, bn_mean, bn_var, W1, b1, W2, b2,
                  sW1, sW2, sB1, sB2);
    for (int i = t; i < NPB * ASTR; i += CBLK) facc[i] = 0.f;
    if (t < NPB) hist[t] = 0;
    __syncthreads();

    const int b = blockIdx.x;
    const int s0 = base[b];
    const int n  = totals[b];

    if (n <= CAP) {
        // phase 1: node histogram
        for (int k = t; k < n; k += CBLK)
            atomicAdd(&hist[sortedG[s0 + k] & (NPB - 1)], 1);
        __syncthreads();

        // phase 2: exclusive scan over NPB counters
        int myh = (t < NPB) ? hist[t] : 0;
        if (t < NPB) off[t] = myh;
        __syncthreads();
        for (int d2 = 1; d2 < NPB; d2 <<= 1) {
            int add = 0;
            if (t < NPB && t >= d2) add = off[t - d2];
            __syncthreads();
            if (t < NPB) off[t] += add;
            __syncthreads();
        }
        if (t < NPB) cur[t] = off[t] - myh;
        __syncthreads();
        if (t < NPB) off[t] = cur[t];
        if (t == 0) off[NPB] = n;
        __syncthreads();

        // phase 3: scatter edge indices into node-sorted (swizzled) LDS order
        for (int k = t; k < n; k += CBLK) {
            unsigned e = sortedG[s0 + k];
            int pos = atomicAdd(&cur[e & (NPB - 1)], 1);
            sorted2[SWZ(pos)] = e >> LOGNPB;
        }
        __syncthreads();

        // phase 4: contiguous-range gather + MLP + register accumulation
        const int per = (n + CBLK - 1) / CBLK;
        int k0 = t * per;
        int k1 = k0 + per; if (k1 > n) k1 = n;
        if (k0 < k1) {
            int cu = 0;
            while (off[cu + 1] <= k0) ++cu;
            int nodeEnd = off[cu + 1];

            float ac[D];
            #pragma unroll
            for (int j = 0; j < D; ++j) ac[j] = 0.f;

            for (int k = k0; k < k1; ++k) {
                if (k >= nodeEnd) {
                    #pragma unroll
                    for (int j = 0; j < D; ++j) {
                        atomicAdd(&facc[cu * ASTR + j], ac[j]);
                        ac[j] = 0.f;
                    }
                    do { ++cu; } while (off[cu + 1] <= k);
                    nodeEnd = off[cu + 1];
                }
                unsigned idx = sorted2[SWZ(k)];
                const float4* p = reinterpret_cast<const float4*>(edges + (long)idx * D);
                float4 c0 = p[0], c1 = p[1], c2 = p[2];
                float x[D] = {c0.x, c0.y, c0.z, c0.w, c1.x, c1.y, c1.z, c1.w,
                              c2.x, c2.y, c2.z, c2.w};
                float h[D];
                #pragma unroll
                for (int j = 0; j < D; ++j) h[j] = sB1[j];
                #pragma unroll
                for (int d = 0; d < D; ++d) {
                    float xd = x[d];
                    #pragma unroll
                    for (int j = 0; j < D; ++j) h[j] = fmaf(xd, sW1[d * D + j], h[j]);
                }
                #pragma unroll
                for (int j = 0; j < D; ++j) h[j] = fmaxf(h[j], 0.f);
                // second GEMM accumulates directly; bias applied at final write
                #pragma unroll
                for (int d = 0; d < D; ++d) {
                    float hd = h[d];
                    #pragma unroll
                    for (int j = 0; j < D; ++j) ac[j] = fmaf(hd, sW2[d * D + j], ac[j]);
                }
            }
            #pragma unroll
            for (int j = 0; j < D; ++j) atomicAdd(&facc[cu * ASTR + j], ac[j]);
        }
    } else {
        // oversized bucket: per-edge atomic path (includes bias; hist stays 0)
        for (int k = t; k < n; k += CBLK) {
            unsigned e = sortedG[s0 + k];
            const float4* p = reinterpret_cast<const float4*>(edges + (long)(e >> LOGNPB) * D);
            float4 c0 = p[0], c1 = p[1], c2 = p[2];
            float x[D] = {c0.x, c0.y, c0.z, c0.w, c1.x, c1.y, c1.z, c1.w,
                          c2.x, c2.y, c2.z, c2.w};
            float y[D];
            mlp12(x, sW1, sW2, sB1, sB2, y);
            int rloc = (int)(e & (NPB - 1));
            #pragma unroll
            for (int j = 0; j < D; ++j) atomicAdd(&facc[rloc * ASTR + j], y[j]);
        }
    }
    __syncthreads();

    long obase = (long)b * (NPB * D);
    long cnt_w = total - obase; if (cnt_w > NPB * D) cnt_w = NPB * D;
    for (long i = t; i < cnt_w; i += CBLK) {
        int node = (int)i / D, j = (int)i % D;
        out[obase + i] = facc[node * ASTR + j] + (float)hist[node] * sB2[j];
    }
}

// ---------------- fallback: direct atomic scatter ----------------
#define EPT 4
__global__ __launch_bounds__(ABLK) void edge_mlp_scatter(
    const float* __restrict__ edges,
    const float* __restrict__ bn_scale, const float* __restrict__ bn_bias,
    const float* __restrict__ bn_mean,  const float* __restrict__ bn_var,
    const float* __restrict__ W1, const float* __restrict__ b1,
    const float* __restrict__ W2, const float* __restrict__ b2,
    const int* __restrict__ receivers, float* __restrict__ out, long E)
{
    __shared__ float sW1[D * D], sW2[D * D], sB1[D], sB2[D];
    const int t = threadIdx.x;
    build_weights(t, bn_scale, bn_bias, bn_mean, bn_var, W1, b1, W2, b2,
                  sW1, sW2, sB1, sB2);
    __syncthreads();
    const long basee = (long)blockIdx.x * (ABLK * EPT) + t;
    #pragma unroll
    for (int kk = 0; kk < EPT; ++kk) {
        long e = basee + (long)kk * ABLK;
        if (e >= E) continue;
        int r = receivers[e];
        const float4* p = reinterpret_cast<const float4*>(edges + e * D);
        float4 v0 = p[0], v1 = p[1], v2 = p[2];
        float x[D] = {v0.x, v0.y, v0.z, v0.w, v1.x, v1.y, v1.z, v1.w,
                      v2.x, v2.y, v2.z, v2.w};
        float y[D];
        mlp12(x, sW1, sW2, sB1, sB2, y);
        #pragma unroll
        for (int j = 0; j < D; ++j) atomicAdd(&out[(long)r * D + j], y[j]);
    }
}

extern "C" void kernel_launch(void* const* d_in, const int* in_sizes, int n_in,
                              void* d_out, int out_size, void* d_ws, size_t ws_size,
                              hipStream_t stream) {
    const float* edges     = (const float*)d_in[0];
    const float* bn_scale  = (const float*)d_in[1];
    const float* bn_bias   = (const float*)d_in[2];
    const float* bn_mean   = (const float*)d_in[3];
    const float* bn_var    = (const float*)d_in[4];
    const float* W1        = (const float*)d_in[5];
    const float* b1        = (const float*)d_in[6];
    const float* W2        = (const float*)d_in[7];
    const float* b2        = (const float*)d_in[8];
    const int*   receivers = (const int*)d_in[9];
    float*       out       = (float*)d_out;

    const long E = (long)in_sizes[0] / D;
    const int  N = out_size / D;

    const int  nbuck = (N + NPB - 1) >> LOGNPB;
    const long nblk  = (E + EPB - 1) / EPB;
    const size_t cntBytes = (size_t)nblk * (size_t)nbuck * 4u;
    const size_t need = cntBytes + 2u * (size_t)nbuck * 4u + (size_t)E * 4u + 512u;
    const long total = (long)N * D;

    const bool shapeOK = (nbuck <= 2048) && (E < (1L << 25));

    if (shapeOK && ws_size >= need) {
        char* w = (char*)d_ws;
        int* cnt    = (int*)w;  w += cntBytes;
        int* totals = (int*)w;  w += (size_t)nbuck * 4u;
        int* basep  = (int*)w;  w += (size_t)nbuck * 4u;
        unsigned int* sortedG = (unsigned int*)w;

        const size_t lds = (size_t)nbuck * 4u;
        passA_hist    <<<dim3((unsigned)nblk), dim3(ABLK), lds, stream>>>(receivers, E, nbuck, cnt);
        passS1_colscan<<<dim3((unsigned)nbuck), dim3(SBLK), 0, stream>>>(cnt, (int)nblk, nbuck, totals);
        passS2_basescan<<<dim3(1), dim3(1024), 0, stream>>>(totals, basep, nbuck);
        passB_scatter <<<dim3((unsigned)nblk), dim3(ABLK), lds, stream>>>(receivers, E, nbuck, cnt, basep, sortedG);
        passC_nodesort<<<dim3((unsigned)nbuck), dim3(CBLK), 0, stream>>>(
            edges, sortedG, basep, totals,
            bn_scale, bn_bias, bn_mean, bn_var, W1, b1, W2, b2, out, total);
        return;
    }

    (void)hipMemsetAsync(d_out, 0, (size_t)out_size * sizeof(float), stream);
    const long blocks = (E + (long)(ABLK * EPT) - 1) / (long)(ABLK * EPT);
    edge_mlp_scatter<<<dim3((unsigned)blocks), dim3(ABLK), 0, stream>>>(
        edges, bn_scale, bn_bias, bn_mean, bn_var, W1, b1, W2, b2,
        receivers, out, E);
}

// Round 10
// 397.698 us; speedup vs baseline: 3.2370x; 1.2226x over previous
//
#include <hip/hip_runtime.h>

#define D      12
#define ASTR   13     // LDS acc stride (coprime with 32 banks)
#define LOGNPB 7
#define NPB    128    // nodes per bucket
#define CAP    9216   // max bucket sub-range held in LDS (mean 8184 + 11 sigma)
#define EPB    16384  // edges per block for passes A/B
#define ABLK   256
#define SBLK   256
#define CBLK   256
#define SPLIT  2      // blocks per bucket in pass C

// involution swizzle for sorted2 (breaks stride-32 bank pattern; applied write+read)
#define SWZ(p) ((p) ^ (((p) >> 5) & 31))

// ---------------- pass A: per-block bucket histogram ----------------
__global__ __launch_bounds__(ABLK) void passA_hist(
    const int* __restrict__ receivers, long E, int nbuck,
    int* __restrict__ cnt /* [nblk][nbuck], row-major */)
{
    extern __shared__ int hist[]; // nbuck ints
    for (int i = threadIdx.x; i < nbuck; i += ABLK) hist[i] = 0;
    __syncthreads();
    long e0 = (long)blockIdx.x * EPB;
    long e1 = e0 + EPB; if (e1 > E) e1 = E;
    for (long e = e0 + threadIdx.x; e < e1; e += ABLK) {
        int r = receivers[e];
        atomicAdd(&hist[r >> LOGNPB], 1);
    }
    __syncthreads();
    int* row = cnt + (long)blockIdx.x * nbuck;
    for (int i = threadIdx.x; i < nbuck; i += ABLK) row[i] = hist[i];
}

// ---------------- pass S1: exclusive scan down each bucket column ----------------
__global__ __launch_bounds__(SBLK) void passS1_colscan(
    int* __restrict__ cnt, int nblk, int nbuck, int* __restrict__ totals)
{
    int b = blockIdx.x;
    int t = threadIdx.x;
    __shared__ int csum[SBLK];
    int per = (nblk + SBLK - 1) / SBLK;
    int i0 = t * per;
    int i1 = i0 + per; if (i1 > nblk) i1 = nblk;
    int s = 0;
    for (int i = i0; i < i1; ++i) s += cnt[(long)i * nbuck + b];
    csum[t] = s;
    __syncthreads();
    for (int off = 1; off < SBLK; off <<= 1) {
        int add = (t >= off) ? csum[t - off] : 0;
        __syncthreads();
        csum[t] += add;
        __syncthreads();
    }
    int run = csum[t] - s;
    for (int i = i0; i < i1; ++i) {
        long a = (long)i * nbuck + b;
        int tmp = cnt[a];
        cnt[a] = run;
        run += tmp;
    }
    if (t == SBLK - 1) totals[b] = csum[SBLK - 1];
}

// ---------------- pass S2: exclusive scan over bucket totals ----------------
__global__ __launch_bounds__(1024) void passS2_basescan(
    const int* __restrict__ totals, int* __restrict__ base, int nbuck)
{
    __shared__ int sh[1024];
    int t = threadIdx.x;
    int v = (t < nbuck) ? totals[t] : 0;
    sh[t] = v;
    __syncthreads();
    for (int off = 1; off < 1024; off <<= 1) {
        int add = (t >= off) ? sh[t - off] : 0;
        __syncthreads();
        sh[t] += add;
        __syncthreads();
    }
    if (t < nbuck) base[t] = sh[t] - v;
}

// ---------------- pass B: scatter edge ids into bucket-sorted order ----------------
__global__ __launch_bounds__(ABLK) void passB_scatter(
    const int* __restrict__ receivers, long E, int nbuck,
    const int* __restrict__ cnt, const int* __restrict__ base,
    unsigned int* __restrict__ sorted)
{
    extern __shared__ int cur[];
    const int* row = cnt + (long)blockIdx.x * nbuck;
    for (int i = threadIdx.x; i < nbuck; i += ABLK) cur[i] = row[i] + base[i];
    __syncthreads();
    long e0 = (long)blockIdx.x * EPB;
    long e1 = e0 + EPB; if (e1 > E) e1 = E;
    for (long e = e0 + threadIdx.x; e < e1; e += ABLK) {
        int r = receivers[e];
        int b = r >> LOGNPB;
        int pos = atomicAdd(&cur[b], 1);
        sorted[pos] = ((unsigned)e << LOGNPB) | (unsigned)(r & (NPB - 1));
    }
}

// -------- helpers --------
__device__ __forceinline__ void build_weights(
    int t,
    const float* __restrict__ bn_scale, const float* __restrict__ bn_bias,
    const float* __restrict__ bn_mean,  const float* __restrict__ bn_var,
    const float* __restrict__ W1, const float* __restrict__ b1,
    const float* __restrict__ W2, const float* __restrict__ b2,
    float* sW1, float* sW2, float* sB1, float* sB2)
{
    if (t < D * D) {
        int d = t / D;
        float a = bn_scale[d] * rsqrtf(bn_var[d] + 1e-5f);
        sW1[t] = a * W1[t];
        sW2[t] = W2[t];
    }
    if (t < D) {
        float acc = b1[t];
        #pragma unroll
        for (int d = 0; d < D; ++d) {
            float a = bn_scale[d] * rsqrtf(bn_var[d] + 1e-5f);
            float c = bn_bias[d] - bn_mean[d] * a;
            acc += c * W1[d * D + t];
        }
        sB1[t] = acc;
        sB2[t] = b2[t];
    }
}

__device__ __forceinline__ void mlp12(
    const float x[D],
    const float* sW1, const float* sW2, const float* sB1, const float* sB2,
    float y[D])
{
    float h[D];
    #pragma unroll
    for (int j = 0; j < D; ++j) h[j] = sB1[j];
    #pragma unroll
    for (int d = 0; d < D; ++d) {
        float xd = x[d];
        #pragma unroll
        for (int j = 0; j < D; ++j) h[j] = fmaf(xd, sW1[d * D + j], h[j]);
    }
    #pragma unroll
    for (int j = 0; j < D; ++j) h[j] = fmaxf(h[j], 0.f);
    #pragma unroll
    for (int j = 0; j < D; ++j) y[j] = sB2[j];
    #pragma unroll
    for (int d = 0; d < D; ++d) {
        float hd = h[d];
        #pragma unroll
        for (int j = 0; j < D; ++j) y[j] = fmaf(hd, sW2[d * D + j], y[j]);
    }
}

// ---------------- pass C: node sort + pairwise 2-deep pipelined register accum ----
// r10: r7 geometry (NPB=128), 2-deep pairwise prefetch (4 rows in flight per
// SIMD at 2 waves), merged 2nd GEMM (no y[12]), b2 bias applied once per node
// at write via phase-1 hist. SPLIT=2 via gridDim.y + partial slabs for tail
// balance. NO launch_bounds occupancy cap (r4/r8: forces spills).
__global__ __launch_bounds__(CBLK) void passC_nodesort(
    const float* __restrict__ edges,
    const unsigned int* __restrict__ sortedG,
    const int* __restrict__ base, const int* __restrict__ totals,
    const float* __restrict__ bn_scale, const float* __restrict__ bn_bias,
    const float* __restrict__ bn_mean,  const float* __restrict__ bn_var,
    const float* __restrict__ W1, const float* __restrict__ b1,
    const float* __restrict__ W2, const float* __restrict__ b2,
    float* __restrict__ part,   // null => write out directly
    float* __restrict__ out,
    long total /* N*D */, long slab /* floats per split slab */)
{
    __shared__ float sW1[D * D], sW2[D * D], sB1[D], sB2[D];
    __shared__ int hist[NPB];
    __shared__ int off[NPB + 1];
    __shared__ int cur[NPB];
    __shared__ unsigned sorted2[CAP];
    __shared__ float facc[NPB * ASTR];

    const int t = threadIdx.x;
    build_weights(t, bn_scale, bn_bias, bn_mean, bn_var, W1, b1, W2, b2,
                  sW1, sW2, sB1, sB2);
    for (int i = t; i < NPB * ASTR; i += CBLK) facc[i] = 0.f;
    if (t < NPB) hist[t] = 0;
    __syncthreads();

    const int b = blockIdx.x;
    const int s = blockIdx.y;
    const int S = gridDim.y;
    const int s0 = base[b];
    const int n  = totals[b];
    const int chunk = (n + S - 1) / S;
    const int g0 = s * chunk;
    int g1 = g0 + chunk; if (g1 > n) g1 = n;
    const int ns = g1 - g0;
    const unsigned* __restrict__ src = sortedG + s0 + g0;

    if (ns > 0 && ns <= CAP) {
        // phase 1: node histogram over this sub-range
        for (int k = t; k < ns; k += CBLK)
            atomicAdd(&hist[src[k] & (NPB - 1)], 1);
        __syncthreads();

        // phase 2: exclusive scan over NPB counters
        int myh = (t < NPB) ? hist[t] : 0;
        if (t < NPB) off[t] = myh;
        __syncthreads();
        for (int d2 = 1; d2 < NPB; d2 <<= 1) {
            int add = 0;
            if (t < NPB && t >= d2) add = off[t - d2];
            __syncthreads();
            if (t < NPB) off[t] += add;
            __syncthreads();
        }
        if (t < NPB) cur[t] = off[t] - myh;
        __syncthreads();
        if (t < NPB) off[t] = cur[t];
        if (t == 0) off[NPB] = ns;
        __syncthreads();

        // phase 3: scatter edge indices into node-sorted (swizzled) LDS order
        for (int k = t; k < ns; k += CBLK) {
            unsigned e = src[k];
            int pos = atomicAdd(&cur[e & (NPB - 1)], 1);
            sorted2[SWZ(pos)] = e >> LOGNPB;
        }
        __syncthreads();

        // phase 4: pairwise 2-deep pipelined gather + MLP + register accum
        const int per = (ns + CBLK - 1) / CBLK;
        int k0 = t * per;
        int k1 = k0 + per; if (k1 > ns) k1 = ns;
        if (k0 < k1) {
            int cu = 0;
            while (off[cu + 1] <= k0) ++cu;
            int nodeEnd = off[cu + 1];

            float ac[D];
            #pragma unroll
            for (int j = 0; j < D; ++j) ac[j] = 0.f;

            auto edge_mlp = [&](float4 c0, float4 c1, float4 c2) {
                float x[D] = {c0.x, c0.y, c0.z, c0.w, c1.x, c1.y, c1.z, c1.w,
                              c2.x, c2.y, c2.z, c2.w};
                float h[D];
                #pragma unroll
                for (int j = 0; j < D; ++j) h[j] = sB1[j];
                #pragma unroll
                for (int d = 0; d < D; ++d) {
                    float xd = x[d];
                    #pragma unroll
                    for (int j = 0; j < D; ++j) h[j] = fmaf(xd, sW1[d * D + j], h[j]);
                }
                #pragma unroll
                for (int j = 0; j < D; ++j) h[j] = fmaxf(h[j], 0.f);
                #pragma unroll
                for (int d = 0; d < D; ++d) {
                    float hd = h[d];
                    #pragma unroll
                    for (int j = 0; j < D; ++j) ac[j] = fmaf(hd, sW2[d * D + j], ac[j]);
                }
            };

            const int kL = k1 - 1;
            // prologue: current pair in flight
            unsigned iA = sorted2[SWZ(k0)];
            unsigned iB = sorted2[SWZ((k0 + 1 <= kL) ? k0 + 1 : kL)];
            const float4* pA = reinterpret_cast<const float4*>(edges + (long)iA * D);
            const float4* pB = reinterpret_cast<const float4*>(edges + (long)iB * D);
            float4 a0 = pA[0], a1 = pA[1], a2 = pA[2];
            float4 b0 = pB[0], b1v = pB[1], b2v = pB[2];

            for (int k = k0; k < k1; k += 2) {
                // issue next pair (clamped duplicates harmless)
                int kn0 = (k + 2 <= kL) ? k + 2 : kL;
                int kn1 = (k + 3 <= kL) ? k + 3 : kL;
                unsigned jA = sorted2[SWZ(kn0)];
                unsigned jB = sorted2[SWZ(kn1)];
                const float4* qA = reinterpret_cast<const float4*>(edges + (long)jA * D);
                const float4* qB = reinterpret_cast<const float4*>(edges + (long)jB * D);
                float4 na0 = qA[0], na1 = qA[1], na2 = qA[2];
                float4 nb0 = qB[0], nb1 = qB[1], nb2 = qB[2];

                if (k >= nodeEnd) {
                    #pragma unroll
                    for (int j = 0; j < D; ++j) {
                        atomicAdd(&facc[cu * ASTR + j], ac[j]);
                        ac[j] = 0.f;
                    }
                    do { ++cu; } while (off[cu + 1] <= k);
                    nodeEnd = off[cu + 1];
                }
                edge_mlp(a0, a1, a2);

                if (k + 1 < k1) {
                    if (k + 1 >= nodeEnd) {
                        #pragma unroll
                        for (int j = 0; j < D; ++j) {
                            atomicAdd(&facc[cu * ASTR + j], ac[j]);
                            ac[j] = 0.f;
                        }
                        do { ++cu; } while (off[cu + 1] <= k + 1);
                        nodeEnd = off[cu + 1];
                    }
                    edge_mlp(b0, b1v, b2v);
                }
                a0 = na0; a1 = na1; a2 = na2;
                b0 = nb0; b1v = nb1; b2v = nb2;
            }
            #pragma unroll
            for (int j = 0; j < D; ++j) atomicAdd(&facc[cu * ASTR + j], ac[j]);
        }
    } else if (ns > 0) {
        // oversized sub-range: per-edge atomic path (bias per-edge; hist stays 0)
        for (int k = t; k < ns; k += CBLK) {
            unsigned e = src[k];
            const float4* p = reinterpret_cast<const float4*>(edges + (long)(e >> LOGNPB) * D);
            float4 c0 = p[0], c1 = p[1], c2 = p[2];
            float x[D] = {c0.x, c0.y, c0.z, c0.w, c1.x, c1.y, c1.z, c1.w,
                          c2.x, c2.y, c2.z, c2.w};
            float y[D];
            mlp12(x, sW1, sW2, sB1, sB2, y);
            int rloc = (int)(e & (NPB - 1));
            #pragma unroll
            for (int j = 0; j < D; ++j) atomicAdd(&facc[rloc * ASTR + j], y[j]);
        }
    }
    __syncthreads();

    // write slab: facc + count*b2 (bias per node, counted in this sub-range's hist)
    if (part != nullptr) {
        float* dst = part + (long)s * slab + (long)b * (NPB * D);
        for (int i = t; i < NPB * D; i += CBLK) {
            int node = i / D, j = i % D;
            dst[i] = facc[node * ASTR + j] + (float)hist[node] * sB2[j];
        }
    } else {
        long obase = (long)b * (NPB * D);
        long cnt_w = total - obase; if (cnt_w > NPB * D) cnt_w = NPB * D;
        for (long i = t; i < cnt_w; i += CBLK) {
            int node = (int)i / D, j = (int)i % D;
            out[obase + i] = facc[node * ASTR + j] + (float)hist[node] * sB2[j];
        }
    }
}

// ---------------- reduce: sum SPLIT partial slabs (float4) ----------------
__global__ __launch_bounds__(CBLK) void reduce_partials(
    const float* __restrict__ part, float* __restrict__ out,
    long total4, long slab4, int S)
{
    long i = (long)blockIdx.x * CBLK + threadIdx.x;
    if (i >= total4) return;
    const float4* p = reinterpret_cast<const float4*>(part);
    float4 v = p[i];
    for (int s = 1; s < S; ++s) {
        float4 w = p[(long)s * slab4 + i];
        v.x += w.x; v.y += w.y; v.z += w.z; v.w += w.w;
    }
    reinterpret_cast<float4*>(out)[i] = v;
}

// ---------------- fallback: direct atomic scatter ----------------
#define EPT 4
__global__ __launch_bounds__(ABLK) void edge_mlp_scatter(
    const float* __restrict__ edges,
    const float* __restrict__ bn_scale, const float* __restrict__ bn_bias,
    const float* __restrict__ bn_mean,  const float* __restrict__ bn_var,
    const float* __restrict__ W1, const float* __restrict__ b1,
    const float* __restrict__ W2, const float* __restrict__ b2,
    const int* __restrict__ receivers, float* __restrict__ out, long E)
{
    __shared__ float sW1[D * D], sW2[D * D], sB1[D], sB2[D];
    const int t = threadIdx.x;
    build_weights(t, bn_scale, bn_bias, bn_mean, bn_var, W1, b1, W2, b2,
                  sW1, sW2, sB1, sB2);
    __syncthreads();
    const long basee = (long)blockIdx.x * (ABLK * EPT) + t;
    #pragma unroll
    for (int kk = 0; kk < EPT; ++kk) {
        long e = basee + (long)kk * ABLK;
        if (e >= E) continue;
        int r = receivers[e];
        const float4* p = reinterpret_cast<const float4*>(edges + e * D);
        float4 v0 = p[0], v1 = p[1], v2 = p[2];
        float x[D] = {v0.x, v0.y, v0.z, v0.w, v1.x, v1.y, v1.z, v1.w,
                      v2.x, v2.y, v2.z, v2.w};
        float y[D];
        mlp12(x, sW1, sW2, sB1, sB2, y);
        #pragma unroll
        for (int j = 0; j < D; ++j) atomicAdd(&out[(long)r * D + j], y[j]);
    }
}

extern "C" void kernel_launch(void* const* d_in, const int* in_sizes, int n_in,
                              void* d_out, int out_size, void* d_ws, size_t ws_size,
                              hipStream_t stream) {
    const float* edges     = (const float*)d_in[0];
    const float* bn_scale  = (const float*)d_in[1];
    const float* bn_bias   = (const float*)d_in[2];
    const float* bn_mean   = (const float*)d_in[3];
    const float* bn_var    = (const float*)d_in[4];
    const float* W1        = (const float*)d_in[5];
    const float* b1        = (const float*)d_in[6];
    const float* W2        = (const float*)d_in[7];
    const float* b2        = (const float*)d_in[8];
    const int*   receivers = (const int*)d_in[9];
    float*       out       = (float*)d_out;

    const long E = (long)in_sizes[0] / D;
    const int  N = out_size / D;

    const int  nbuck = (N + NPB - 1) >> LOGNPB;
    const long nblk  = (E + EPB - 1) / EPB;
    const size_t cntBytes  = (size_t)nblk * (size_t)nbuck * 4u;
    const size_t slabBytes = (size_t)nbuck * (size_t)(NPB * D) * 4u;
    const size_t baseNeed  = cntBytes + 2u * (size_t)nbuck * 4u + (size_t)E * 4u + 512u;
    const size_t fullNeed  = baseNeed + (size_t)SPLIT * slabBytes + 256u;
    const long total = (long)N * D;

    const bool shapeOK = (nbuck <= 1024) && (E < (1L << 25));

    if (shapeOK && ws_size >= baseNeed) {
        const int S = (ws_size >= fullNeed) ? SPLIT : 1;

        char* w = (char*)d_ws;
        int* cnt    = (int*)w;  w += cntBytes;
        int* totals = (int*)w;  w += (size_t)nbuck * 4u;
        int* basep  = (int*)w;  w += (size_t)nbuck * 4u;
        unsigned int* sortedG = (unsigned int*)w;  w += (size_t)E * 4u;
        float* part = (S > 1) ? (float*)(((uintptr_t)w + 255u) & ~(uintptr_t)255u) : nullptr;

        const size_t lds = (size_t)nbuck * 4u;
        const long slab = (long)nbuck * (NPB * D);

        passA_hist    <<<dim3((unsigned)nblk), dim3(ABLK), lds, stream>>>(receivers, E, nbuck, cnt);
        passS1_colscan<<<dim3((unsigned)nbuck), dim3(SBLK), 0, stream>>>(cnt, (int)nblk, nbuck, totals);
        passS2_basescan<<<dim3(1), dim3(1024), 0, stream>>>(totals, basep, nbuck);
        passB_scatter <<<dim3((unsigned)nblk), dim3(ABLK), lds, stream>>>(receivers, E, nbuck, cnt, basep, sortedG);
        passC_nodesort<<<dim3((unsigned)nbuck, (unsigned)S), dim3(CBLK), 0, stream>>>(
            edges, sortedG, basep, totals,
            bn_scale, bn_bias, bn_mean, bn_var, W1, b1, W2, b2,
            part, out, total, slab);
        if (S > 1) {
            const long total4 = total / 4;
            const long rblocks = (total4 + CBLK - 1) / CBLK;
            reduce_partials<<<dim3((unsigned)rblocks), dim3(CBLK), 0, stream>>>(
                part, out, total4, slab / 4, S);
        }
        return;
    }

    (void)hipMemsetAsync(d_out, 0, (size_t)out_size * sizeof(float), stream);
    const long blocks = (E + (long)(ABLK * EPT) - 1) / (long)(ABLK * EPT);
    edge_mlp_scatter<<<dim3((unsigned)blocks), dim3(ABLK), 0, stream>>>(
        edges, bn_scale, bn_bias, bn_mean, bn_var, W1, b1, W2, b2,
        receivers, out, E);
}